// Round 20
// baseline (608.241 us; speedup 1.0000x reference)
//
#include <hip/hip_runtime.h>

typedef unsigned short u16;
typedef unsigned int u32;
typedef __bf16 bf16x8 __attribute__((ext_vector_type(8)));
typedef float f32x4 __attribute__((ext_vector_type(4)));

#define NHEAD 28
#define NKVH 4
#define HD 128
#define NB 2
#define NS 2048
#define NTOK 4096
#define HIDDEN_DIM 3584
#define QKVW 4608
#define QSZ 3584
#define KOFF 3584
#define VOFF 4096
#define VSLAB (NTOK * 512)
#define NJOBS 896
#define ATTN_BLOCKS 768
// QSCALE * log2(e): softmax runs in exp2 domain (v_exp_f32 is 2^x)
#define QSCALE_L2E 0.12751744f

__device__ __forceinline__ float bf2f(u16 u) {
  u32 x = ((u32)u) << 16; float f; __builtin_memcpy(&f, &x, 4); return f;
}
__device__ __forceinline__ u16 f2bf(float f) {
  u32 x; __builtin_memcpy(&x, &f, 4);
  x += 0x7FFFu + ((x >> 16) & 1u);
  return (u16)(x >> 16);
}
// native cast pair -> v_cvt_pk_bf16_f32 (compiler-fused; RNE)
__device__ __forceinline__ u32 pack2bf(float a, float b) {
  __bf16 lo = (__bf16)a, hi = (__bf16)b;
  u16 ul, uh;
  __builtin_memcpy(&ul, &lo, 2); __builtin_memcpy(&uh, &hi, 2);
  return (u32)ul | ((u32)uh << 16);
}
__device__ __forceinline__ void async16(const void* g, void* lds) {
  __builtin_amdgcn_global_load_lds((const __attribute__((address_space(1))) void*)g,
                                   (__attribute__((address_space(3))) void*)lds,
                                   16, 0, 0);
}

#define SB __builtin_amdgcn_sched_barrier(0)
#define BAR do { SB; __builtin_amdgcn_s_barrier(); SB; } while (0)

// ---------------- elementwise f32 -> bf16 cast (4 elems/thread) ----------------
__global__ void cast_f32_bf16(const float* __restrict__ in, u16* __restrict__ out) {
  int i = (blockIdx.x * 256 + threadIdx.x) * 4;
  float4 v = *(const float4*)(in + i);
  u32 p0 = (u32)f2bf(v.x) | ((u32)f2bf(v.y) << 16);
  u32 p1 = (u32)f2bf(v.z) | ((u32)f2bf(v.w) << 16);
  uint2 r; r.x = p0; r.y = p1;
  *(uint2*)(out + i) = r;
}

// ------------- tiled transpose + cast: in f32 [R][C] -> out bf16 [C][R] --------
// Write phase packs 4 rows per thread into one uint2 (8B) store.
__global__ void transpose_cast(const float* __restrict__ in, u16* __restrict__ out,
                               int R, int C) {
  __shared__ float tile[32][33];
  const int tx = threadIdx.x & 31, ty = threadIdx.x >> 5;   // 32 x 8 read map
  const int c0 = blockIdx.x * 32, r0 = blockIdx.y * 32;
#pragma unroll
  for (int i = 0; i < 32; i += 8)
    tile[ty + i][tx] = in[(size_t)(r0 + ty + i) * C + c0 + tx];
  __syncthreads();
  // write map: 32 cols x 8 row-groups (4 rows each) -> one uint2 per thread
  const int cl = threadIdx.x >> 3, rg = threadIdx.x & 7;
  const int rb = rg * 4;
  uint2 rr;
  rr.x = pack2bf(tile[rb + 0][cl], tile[rb + 1][cl]);
  rr.y = pack2bf(tile[rb + 2][cl], tile[rb + 3][cl]);
  *(uint2*)(out + (size_t)(c0 + cl) * R + r0 + rb) = rr;
}

// ------- rope cos/sin table: [NTOK][64] each; also zeroes the attn job ctr -----
__global__ void rope_table(const int* __restrict__ positions,
                           float* __restrict__ cs, float* __restrict__ sn,
                           int* __restrict__ ctr) {
  if (blockIdx.x == 0 && threadIdx.x == 0) *ctr = 0;
  int idx = blockIdx.x * 256 + threadIdx.x;   // NTOK*64
  int t = idx >> 6, i = idx & 63;
  float p = (float)positions[t];
  float inv = expf(-(float)i * (13.815510557964274f / 64.f));
  float a = p * inv;
  cs[idx] = cosf(a);
  sn[idx] = sinf(a);
}

// --------- in-place RoPE on qkv (q scaled by D^-0.5 * log2e for exp2-softmax) --
// Vectorized: 16 threads per head-row; uint2 loads/stores + float4 cos/sin.
__global__ void rope_kernel(u16* __restrict__ qkv, const float* __restrict__ cs,
                            const float* __restrict__ sn) {
  const int gtid = blockIdx.x * 256 + threadIdx.x;
  const int hr = gtid >> 4;              // head-row id: NTOK*32
  const int sub = gtid & 15;
  const int t = hr >> 5, hh = hr & 31;
  const size_t base = (size_t)t * QKVW +
                      (hh < NHEAD ? hh * HD : KOFF + (hh - NHEAD) * HD);
  const int d0 = sub * 4;
  uint2 xa = *(const uint2*)(qkv + base + d0);        // x1[d0..d0+3]
  uint2 xb = *(const uint2*)(qkv + base + 64 + d0);   // x2[d0..d0+3]
  float4 c = *(const float4*)(cs + t * 64 + d0);
  float4 s = *(const float4*)(sn + t * 64 + d0);
  float x1[4], x2[4];
  x1[0] = bf2f((u16)xa.x); x1[1] = bf2f((u16)(xa.x >> 16));
  x1[2] = bf2f((u16)xa.y); x1[3] = bf2f((u16)(xa.y >> 16));
  x2[0] = bf2f((u16)xb.x); x2[1] = bf2f((u16)(xb.x >> 16));
  x2[2] = bf2f((u16)xb.y); x2[3] = bf2f((u16)(xb.y >> 16));
  const float cc[4] = {c.x, c.y, c.z, c.w};
  const float ss[4] = {s.x, s.y, s.z, s.w};
  const float sc = (hh < NHEAD) ? QSCALE_L2E : 1.0f;
  float y1[4], y2[4];
#pragma unroll
  for (int i = 0; i < 4; ++i) {
    y1[i] = (x1[i] * cc[i] - x2[i] * ss[i]) * sc;
    y2[i] = (x2[i] * cc[i] + x1[i] * ss[i]) * sc;
  }
  uint2 ra, rb;
  ra.x = pack2bf(y1[0], y1[1]); ra.y = pack2bf(y1[2], y1[3]);
  rb.x = pack2bf(y2[0], y2[1]); rb.y = pack2bf(y2[2], y2[3]);
  *(uint2*)(qkv + base + d0) = ra;
  *(uint2*)(qkv + base + 64 + d0) = rb;
}

// ---------------- 256x256 8-phase MFMA GEMM (m201-class template) --------------
// A [M][Kst] bf16, Bt [Next-rows][Kst] bf16. BK=64, 8 waves (2M x 4N).
// LDS: 2 slots x (A 256x64 + B 256x64) = 128 KiB. Per K-tile: 4 quadrant phases
// of 16 MFMA; one 16KB half staged per phase; counted vmcnt(4) once per tile.
// T2 swizzle slot^=row&7 (pre-swizzled source + XOR read). XCD block swizzle.
// MODE 0: bf16 + bias out (stride ldc).  MODE 1: f32 out (stride ldc).
// MODE 2: split-K f32 partial — grid = tiles x slices; slice ks covers
//         k in [ks*NT*64, (ks+1)*NT*64), output slab at outf + ks*M*Next.
template <int MODE>
__global__ __launch_bounds__(512, 2) void gemm256(
    const u16* __restrict__ A, const u16* __restrict__ Bt,
    const float* __restrict__ bias, u16* __restrict__ outb,
    float* __restrict__ outf, int M, int Next, int Kst, int ldc, int NT) {
  __shared__ __align__(16) u16 Al[2][256 * 64];   // 64 KiB
  __shared__ __align__(16) u16 Bl[2][256 * 64];   // 64 KiB
  const int tid = threadIdx.x;
  const int l = tid & 63, w = tid >> 6;
  const int g = l >> 4, r = l & 15;
  const int wm = w >> 2, wn = w & 3;
  const int nbx = Next >> 8;
  const int cpx = (int)gridDim.x >> 3;            // grid % 8 == 0
  const int bid = ((int)blockIdx.x & 7) * cpx + ((int)blockIdx.x >> 3);
  int bx, by, kbase;
  float* outp = outf;
  if (MODE == 2) {
    const int tps = nbx * (M >> 8);               // tiles per K-slice
    const int ks = bid / tps, rem = bid % tps;
    by = rem / nbx; bx = rem % nbx;
    kbase = ks * (NT << 6);
    outp = outf + (size_t)ks * M * Next;
  } else {
    bx = bid % nbx; by = bid / nbx; kbase = 0;
  }
  const int row0 = by * 256, col0 = bx * 256;

  f32x4 acc[8][4] = {};
  bf16x8 af[4][2];        // A-frags: 4 row-frags x 2 k-halves (one rh quadrant)
  bf16x8 bfr[2][2][2];    // B-frags: [ch][fc][kk] — both col-quadrants held

  // stage one 16KB half (128 rows x 64 k) of A or B for k-tile t
  auto stageU = [&](const u16* mb, int base0, char* ldsMat, int h, int t) {
#pragma unroll
    for (int q = 0; q < 2; ++q) {
      const int idx = q * 512 + tid;              // 0..1023 16B-chunks
      const int rho = h * 128 + (idx >> 3);       // row within 256-row tile
      const int sl = (idx & 7) ^ (rho & 7);       // pre-swizzled source slot
      async16(mb + (size_t)(base0 + rho) * Kst + kbase + t * 64 + sl * 8,
              ldsMat + (size_t)(t & 1) * 32768 + h * 16384 + idx * 16);
    }
  };

#define READ_A(s, rh)                                                           \
  _Pragma("unroll") for (int fr = 0; fr < 4; ++fr) {                            \
    const int row_ = (rh) * 128 + wm * 64 + fr * 16 + r;                        \
    _Pragma("unroll") for (int kk = 0; kk < 2; ++kk) {                          \
      const int sl_ = (kk * 4 + g) ^ (row_ & 7);                                \
      af[fr][kk] = *(const bf16x8*)((const char*)Al + (s) * 32768 +             \
                                    row_ * 128 + sl_ * 16);                     \
    }                                                                           \
  }
#define READ_B(s, ch)                                                           \
  _Pragma("unroll") for (int fc = 0; fc < 2; ++fc) {                            \
    const int col_ = (ch) * 128 + wn * 32 + fc * 16 + r;                        \
    _Pragma("unroll") for (int kk = 0; kk < 2; ++kk) {                          \
      const int sl_ = (kk * 4 + g) ^ (col_ & 7);                                \
      bfr[ch][fc][kk] = *(const bf16x8*)((const char*)Bl + (s) * 32768 +        \
                                         col_ * 128 + sl_ * 16);                \
    }                                                                           \
  }
#define MFMA_Q(rh, ch)                                                          \
  __builtin_amdgcn_s_setprio(1);                                                \
  _Pragma("unroll") for (int fr = 0; fr < 4; ++fr)                              \
  _Pragma("unroll") for (int fc = 0; fc < 2; ++fc)                              \
  _Pragma("unroll") for (int kk = 0; kk < 2; ++kk)                              \
    acc[(rh) * 4 + fr][(ch) * 2 + fc] = __builtin_amdgcn_mfma_f32_16x16x32_bf16( \
        af[fr][kk], bfr[ch][fc][kk], acc[(rh) * 4 + fr][(ch) * 2 + fc], 0, 0, 0);\
  __builtin_amdgcn_s_setprio(0);

  // ---- prologue: tile0 full + tile1 A0,B0; counted drain leaves 4 in flight ---
  stageU(A, row0, (char*)Al, 0, 0); stageU(A, row0, (char*)Al, 1, 0);
  stageU(Bt, col0, (char*)Bl, 0, 0); stageU(Bt, col0, (char*)Bl, 1, 0);
  stageU(A, row0, (char*)Al, 0, 1); stageU(Bt, col0, (char*)Bl, 0, 1);
  SB; asm volatile("s_waitcnt vmcnt(4)" ::: "memory");
  BAR;

  for (int t = 0; t < NT; ++t) {
    const int s = t & 1;
    // phase 1: quad(rh0,ch0); stage A-h1(t+1)
    READ_A(s, 0); READ_B(s, 0);
    if (t + 1 < NT) stageU(A, row0, (char*)Al, 1, t + 1);
    BAR; MFMA_Q(0, 0); BAR;
    // phase 2: quad(rh0,ch1); stage B-h1(t+1)
    READ_B(s, 1);
    if (t + 1 < NT) stageU(Bt, col0, (char*)Bl, 1, t + 1);
    BAR; MFMA_Q(0, 1); BAR;
    // phase 3: quad(rh1,ch0); stage A-h0(t+2)
    READ_A(s, 1);
    if (t + 2 < NT) stageU(A, row0, (char*)Al, 0, t + 2);
    BAR; MFMA_Q(1, 0); BAR;
    // phase 4: quad(rh1,ch1); stage B-h0(t+2)
    if (t + 2 < NT) stageU(Bt, col0, (char*)Bl, 0, t + 2);
    BAR; MFMA_Q(1, 1);
    if (t < NT - 2)        { SB; asm volatile("s_waitcnt vmcnt(4)" ::: "memory"); }
    else if (t == NT - 2)  { SB; asm volatile("s_waitcnt vmcnt(0)" ::: "memory"); }
    BAR;
  }
  SB; asm volatile("s_waitcnt vmcnt(0)" ::: "memory");

  // ---- epilogue ----
#pragma unroll
  for (int m = 0; m < 8; ++m) {
    const int row = row0 + (m >> 2) * 128 + wm * 64 + (m & 3) * 16 + g * 4;
#pragma unroll
    for (int n = 0; n < 4; ++n) {
      const int col = col0 + (n >> 1) * 128 + wn * 32 + (n & 1) * 16 + r;
      const float bb = (MODE == 0) ? bias[col] : 0.f;
#pragma unroll
      for (int j = 0; j < 4; ++j) {
        float v = acc[m][n][j] + bb;
        if (MODE == 0) outb[(size_t)(row + j) * ldc + col] = f2bf(v);
        else           outp[(size_t)(row + j) * ldc + col] = v;
      }
    }
  }
}

// ------- V reduce: sum 4 split-K slabs [NTOK][512] f32 + bias -> vtg bf16 ------
// vtg layout [(b*NKVH+kvh)*HD + d][NS]  (transposed via LDS tile)
__global__ void v_reduce(const float* __restrict__ slabs, const float* __restrict__ bias,
                         u16* __restrict__ vtg) {
  __shared__ float tile[32][33];
  const int tx = threadIdx.x & 31, ty = threadIdx.x >> 5;  // 32 x 8
  const int c0 = blockIdx.x * 32;      // col within 512 (kvh*HD+d)
  const int r0 = blockIdx.y * 32;      // token row within NTOK
#pragma unroll
  for (int i = 0; i < 32; i += 8) {
    const size_t idx = (size_t)(r0 + ty + i) * 512 + c0 + tx;
    float s = slabs[idx] + slabs[idx + VSLAB] + slabs[idx + 2 * VSLAB] +
              slabs[idx + 3 * VSLAB];
    tile[ty + i][tx] = s + bias[VOFF + c0 + tx];
  }
  __syncthreads();
#pragma unroll
  for (int i = 0; i < 32; i += 8) {
    const int col = c0 + ty + i;               // kvh = col>>7, d = col&127
    const int row = r0 + tx;                   // b = row>>11, s = row&2047
    vtg[((size_t)((((row >> 11) * NKVH) + (col >> 7)) * HD + (col & 127))) * NS +
        (row & 2047)] = f2bf(tile[tx][ty + i]);
  }
}

// ---------------- causal GQA flash attention (swapped-operand form) ------------
// PERSISTENT blocks + dynamic heavy-first queue; 8 waves, QBLK=128, KVBLK=64.
// K double-buffered in LDS (single wait+barrier per tile for the buffer flip).
// V is NOT staged: PV B-frags are direct 16B global gathers from vtg [d][s]
// (per-(b,kvh) V slice = 512KB L2-resident; a block's 8 waves re-read the same
// 16KB tile -> L1-served). Round-16 audit showed the LDS pipe ~95% saturated
// serving K+V+bpermutes; this splits the load across LDS (K) and L1/L2 (V).
// LDS 32KB -> 768 blocks (3/CU, 24 waves/CU). Deferred softmax.
// (Rounds 14/17: fewer-waves variants are VGPR-walled; round 13: V-dbuf in
// LDS was neutral — the pipe, not the latency, was the wall.)
__global__ __launch_bounds__(512) void attn_kernel(const u16* __restrict__ qkv,
                                                   const u16* __restrict__ vtg,
                                                   u16* __restrict__ Oh,
                                                   int* __restrict__ ctr) {
  __shared__ __align__(16) u16 Ks[2][64 * 128];   // [key][d] swizzled, 16KB each
  __shared__ int s_job;
  const int tid = threadIdx.x, l = tid & 63, w = tid >> 6;   // w 0..7
  const int g = l >> 4, r = l & 15;
  // shuffle sources for the P exchange (same r, groups 2(g&1) and 2(g&1)+1)
  const int srcA = r + ((l & 16) << 1);
  const int srcB = srcA + 16;
  const bool hi = (l & 32) != 0;                 // g>>1

  for (;;) {
    if (tid == 0) s_job = atomicAdd(ctr, 1);
    __syncthreads();                             // also guards LDS reuse across jobs
    const int jid = s_job;
    if (jid >= NJOBS) return;
    const int qtr = jid / 56;
    const int qt = 15 - qtr;                     // heavy jobs grabbed first
    const int bh = jid - qtr * 56;
    const int h = bh % NHEAD, b = bh / NHEAD;
    const int kvh = h / 7;
    const int q0 = qt * 128;

    // Q fragment (B-frag role: col = r = q-row, k = ks*32 + g*8 + i)
    const int qrow = q0 + w * 16 + r;
    const size_t qbase = (size_t)(b * NS + qrow) * QKVW + h * HD;
    bf16x8 qf[4];
#pragma unroll
    for (int ks = 0; ks < 4; ++ks)
      qf[ks] = *(const bf16x8*)(qkv + qbase + ks * 32 + g * 8);

    const u16* kb0 = qkv + (size_t)(b * NS) * QKVW + KOFF + kvh * HD;
    // per-lane V gather base: row d = dt*16+r, keys kv0 + ks2*32 + g*8
    const u16* vpl = vtg + (size_t)((b * NKVH + kvh) * HD + r) * NS + g * 8;

    // per-thread K staging pointers (advance by constant stride per tile)
    const u16* kap[2];
#pragma unroll
    for (int i = 0; i < 2; ++i) {
      const int li = (w * 2 + i) * 64 + l;       // 0..1023 chunk id
      const int rr = li >> 4, c = li & 15;
      kap[i] = kb0 + (size_t)rr * QKVW + ((c ^ (rr & 7)) << 3);
    }

    f32x4 oacc[8] = {};         // O^T: oacc[dt][j] = O[qrow=r][d=dt*16+4g+j]
    float mrun = -1e30f, lsum = 0.f;

    const int nkv = 2 * qt + 2;

    auto stageK = [&](u16* kdst) {
#pragma unroll
      for (int i = 0; i < 2; ++i) {
        async16(kap[i], (char*)kdst + (w * 2 + i) * 1024);
        kap[i] += 64 * QKVW;
      }
    };

    // prologue: K(0)
    stageK(Ks[0]);
    int cur = 0;

    for (int kvt = 0; kvt < nkv; ++kvt) {
      const int kv0 = kvt * 64;
      // per-tile sync: my K[cur] chunks landed (V gathers from the previous
      // tile were register-consumed before their PV MFMAs); barrier =>
      // everyone's K[cur] landed AND K[cur^1] fully read last iter.
      asm volatile("s_waitcnt vmcnt(0)" ::: "memory");
      __builtin_amdgcn_s_barrier();
      __builtin_amdgcn_sched_barrier(0);

      const bool haveNext = (kvt + 1 < nkv);
      if (haveNext) stageK(Ks[cur ^ 1]);

      // wave fully below this KV tile? (rows all masked) -> skip compute
      const bool active = kv0 <= q0 + w * 16 + 15;

      if (active) {
        // ---- QK^T swapped: sacc[n] = S^T[key=n*16+4g+j][qrow=r] ----
        f32x4 sacc[4] = {};
        const char* ksB = (const char*)Ks[cur];
        __builtin_amdgcn_s_setprio(1);
#pragma unroll
        for (int n = 0; n < 4; ++n) {
          const int key = n * 16 + r;
          const int sw = (key & 7) << 4;
#pragma unroll
          for (int ks = 0; ks < 4; ++ks) {
            bf16x8 kf = *(const bf16x8*)(ksB + key * 256 + ((ks * 64 + g * 16) ^ sw));
            sacc[n] = __builtin_amdgcn_mfma_f32_16x16x32_bf16(kf, qf[ks], sacc[n], 0, 0, 0);
          }
        }
        __builtin_amdgcn_s_setprio(0);
        // ---- causal mask (exact per-wave diagonal predicate) ----
        if (kv0 + 63 > q0 + w * 16) {
#pragma unroll
          for (int n = 0; n < 4; ++n) {
            const int key_g = kv0 + n * 16 + g * 4;
#pragma unroll
            for (int j = 0; j < 4; ++j)
              if (key_g + j > qrow) sacc[n][j] = -1e30f;
          }
        }
        // ---- per-lane online softmax (exp2 domain), deferred reductions ----
        float mx = fmaxf(fmaxf(sacc[0][0], sacc[0][1]), fmaxf(sacc[0][2], sacc[0][3]));
#pragma unroll
        for (int n = 1; n < 4; ++n)
          mx = fmaxf(mx, fmaxf(fmaxf(sacc[n][0], sacc[n][1]), fmaxf(sacc[n][2], sacc[n][3])));
        if (!__all(mx <= mrun + 8.0f)) {        // rare: row max grew
          mx = fmaxf(mx, __shfl_xor(mx, 16, 64));
          mx = fmaxf(mx, __shfl_xor(mx, 32, 64));   // row-uniform max
          const float mnew = fmaxf(mrun, mx);
          const float scale = __builtin_amdgcn_exp2f(mrun - mnew);
          mrun = mnew;
          lsum *= scale;
#pragma unroll
          for (int dt = 0; dt < 8; ++dt) oacc[dt] *= scale;
        }
#pragma unroll
        for (int n = 0; n < 4; ++n)
#pragma unroll
          for (int j = 0; j < 4; ++j) {
            float p = __builtin_amdgcn_exp2f(sacc[n][j] - mrun);  // bounded 2^8
            sacc[n][j] = p;
            lsum += p;
          }

        // ---- pack P to bf16 pairs (v_cvt_pk), exchange to PV B-frags in-reg ----
        u32 pk[4][2];
#pragma unroll
        for (int n = 0; n < 4; ++n) {
          pk[n][0] = pack2bf(sacc[n][0], sacc[n][1]);
          pk[n][1] = pack2bf(sacc[n][2], sacc[n][3]);
        }
        union { u32 wrd[4]; bf16x8 v; } pf[2];
#pragma unroll
        for (int ks2 = 0; ks2 < 2; ++ks2) {
          const int n0 = 2 * ks2, n1 = 2 * ks2 + 1;
#pragma unroll
          for (int hh2 = 0; hh2 < 2; ++hh2) {
            u32 a0 = (u32)__shfl((int)pk[n0][hh2], srcA, 64);
            u32 a1 = (u32)__shfl((int)pk[n1][hh2], srcA, 64);
            pf[ks2].wrd[hh2] = hi ? a1 : a0;
            u32 b0 = (u32)__shfl((int)pk[n0][hh2], srcB, 64);
            u32 b1 = (u32)__shfl((int)pk[n1][hh2], srcB, 64);
            pf[ks2].wrd[2 + hh2] = hi ? b1 : b0;
          }
        }

        // ---- PV swapped: V^T B-frags gathered direct from global (L1/L2) ----
        const u16* vtb = vpl + kv0;
        __builtin_amdgcn_s_setprio(1);
#pragma unroll
        for (int ks2 = 0; ks2 < 2; ++ks2) {
#pragma unroll
          for (int dt = 0; dt < 8; ++dt) {
            bf16x8 vf = *(const bf16x8*)(vtb + (size_t)dt * (16 * NS) + ks2 * 32);
            oacc[dt] = __builtin_amdgcn_mfma_f32_16x16x32_bf16(vf, pf[ks2].v, oacc[dt], 0, 0, 0);
          }
        }
        __builtin_amdgcn_s_setprio(0);
      }
      cur ^= 1;
    }

    // ---- epilogue: reduce l across the row's 4 lanes, write O^T -> Oh ----
    float lr = lsum;
    lr += __shfl_xor(lr, 16, 64);
    lr += __shfl_xor(lr, 32, 64);
    const float inv = 1.f / lr;
    const size_t obase = (size_t)(b * NS + qrow) * QSZ + h * HD;
#pragma unroll
    for (int dt = 0; dt < 8; ++dt) {
      uint2 r2;
      r2.x = pack2bf(oacc[dt][0] * inv, oacc[dt][1] * inv);
      r2.y = pack2bf(oacc[dt][2] * inv, oacc[dt][3] * inv);
      *(uint2*)(Oh + obase + dt * 16 + 4 * g) = r2;
    }
  }
}

// -------------------------------------------------------------------------------
extern "C" void kernel_launch(void* const* d_in, const int* in_sizes, int n_in,
                              void* d_out, int out_size, void* d_ws, size_t ws_size,
                              hipStream_t stream) {
  const int* positions = (const int*)d_in[0];
  const float* hidden = (const float*)d_in[1];
  const float* w_qkv = (const float*)d_in[2];
  const float* b_qkv = (const float*)d_in[3];
  const float* w_o = (const float*)d_in[4];
  float* out = (float*)d_out;

  char* ws = (char*)d_ws;
  const size_t XB_OFF = 0;                           // 29,360,128 B (later reused by WoT)
  const size_t WQT_OFF = 29360128;                   // 33,030,144 B (later reused by Oh)
  const size_t QKV_OFF = WQT_OFF + 33030144;         // 37,748,736 B
  const size_t CS_OFF = QKV_OFF + 37748736;          // 1,048,576 B
  const size_t SN_OFF = CS_OFF + 1048576;            // 1,048,576 B
  const size_t CTR_OFF = SN_OFF + 1048576;           // 64 B (attn job counter)
  const size_t WS_NEED = CTR_OFF + 64;               // ~102.2 MB (known-safe)
  if (ws_size < WS_NEED) return;

  u16* Xb = (u16*)(ws + XB_OFF);
  u16* WoT = (u16*)(ws + XB_OFF);    // alias: after GEMMs consumed Xb
  u16* WqT = (u16*)(ws + WQT_OFF);
  u16* Oh = (u16*)(ws + WQT_OFF);    // alias: after GEMMs consumed WqT
  u16* qkvb = (u16*)(ws + QKV_OFF);
  float* cs = (float*)(ws + CS_OFF);
  float* sn = (float*)(ws + SN_OFF);
  int* ctr = (int*)(ws + CTR_OFF);
  // d_out scratch: vtg (4MB) + 4 split-K V slabs (32MB); GEMM2 overwrites later.
  u16* vtg = (u16*)d_out;
  float* vslabs = (float*)((char*)d_out + 4194304);

  cast_f32_bf16<<<14336, 256, 0, stream>>>(hidden, Xb);
  transpose_cast<<<dim3(QKVW / 32, HIDDEN_DIM / 32), 256, 0, stream>>>(w_qkv, WqT, HIDDEN_DIM, QKVW);
  rope_table<<<(NTOK * 64) / 256, 256, 0, stream>>>(positions, cs, sn, ctr);

  // Q+K projection (+bias): N extent 4096 -> grid 16x16 = 256, zero tail
  gemm256<0><<<256, 512, 0, stream>>>(
      Xb, WqT, b_qkv, qkvb, nullptr, NTOK, 4096, HIDDEN_DIM, QKVW, HIDDEN_DIM / 64);

  // V projection: split-K=4 partials (grid 2x16 tiles x 4 slices = 128 blocks)
  gemm256<2><<<128, 512, 0, stream>>>(
      Xb, WqT + (size_t)VOFF * HIDDEN_DIM, nullptr, nullptr, vslabs,
      NTOK, 512, HIDDEN_DIM, 512, HIDDEN_DIM / 64 / 4);

  // reduce slabs + bias -> vtg (transposed [b,kvh,d][s])
  v_reduce<<<dim3(512 / 32, NTOK / 32), 256, 0, stream>>>(vslabs, b_qkv, vtg);

  // vectorized RoPE on Q,K: 16 threads/head-row, 8192 blocks
  rope_kernel<<<(NTOK * 32 * 16) / 256, 256, 0, stream>>>(qkvb, cs, sn);

  transpose_cast<<<dim3(HIDDEN_DIM / 32, QSZ / 32), 256, 0, stream>>>(w_o, WoT, QSZ, HIDDEN_DIM);

  // persistent attn: 768 blocks (3/CU at 32KB LDS), V gathered from L1/L2
  attn_kernel<<<ATTN_BLOCKS, 512, 0, stream>>>(qkvb, vtg, Oh, ctr);

  gemm256<1><<<(HIDDEN_DIM / 256) * (NTOK / 256), 512, 0, stream>>>(
      Oh, WoT, nullptr, nullptr, out, NTOK, HIDDEN_DIM, QSZ, HIDDEN_DIM, QSZ / 64);
}

// Round 21
// 433.935 us; speedup vs baseline: 1.4017x; 1.4017x over previous
//
#include <hip/hip_runtime.h>

typedef unsigned short u16;
typedef unsigned int u32;
typedef __bf16 bf16x8 __attribute__((ext_vector_type(8)));
typedef float f32x4 __attribute__((ext_vector_type(4)));

#define NHEAD 28
#define NKVH 4
#define HD 128
#define NB 2
#define NS 2048
#define NTOK 4096
#define HIDDEN_DIM 3584
#define QKVW 4608
#define QSZ 3584
#define KOFF 3584
#define VOFF 4096
#define VSLAB (NTOK * 512)
#define NJOBS 896
#define ATTN_BLOCKS 512
// QSCALE * log2(e): softmax runs in exp2 domain (v_exp_f32 is 2^x)
#define QSCALE_L2E 0.12751744f

__device__ __forceinline__ float bf2f(u16 u) {
  u32 x = ((u32)u) << 16; float f; __builtin_memcpy(&f, &x, 4); return f;
}
__device__ __forceinline__ u16 f2bf(float f) {
  u32 x; __builtin_memcpy(&x, &f, 4);
  x += 0x7FFFu + ((x >> 16) & 1u);
  return (u16)(x >> 16);
}
// native cast pair -> v_cvt_pk_bf16_f32 (compiler-fused; RNE)
__device__ __forceinline__ u32 pack2bf(float a, float b) {
  __bf16 lo = (__bf16)a, hi = (__bf16)b;
  u16 ul, uh;
  __builtin_memcpy(&ul, &lo, 2); __builtin_memcpy(&uh, &hi, 2);
  return (u32)ul | ((u32)uh << 16);
}
__device__ __forceinline__ void async16(const void* g, void* lds) {
  __builtin_amdgcn_global_load_lds((const __attribute__((address_space(1))) void*)g,
                                   (__attribute__((address_space(3))) void*)lds,
                                   16, 0, 0);
}

#define SB __builtin_amdgcn_sched_barrier(0)
#define BAR do { SB; __builtin_amdgcn_s_barrier(); SB; } while (0)

// ---------------- elementwise f32 -> bf16 cast (4 elems/thread) ----------------
__global__ void cast_f32_bf16(const float* __restrict__ in, u16* __restrict__ out) {
  int i = (blockIdx.x * 256 + threadIdx.x) * 4;
  float4 v = *(const float4*)(in + i);
  u32 p0 = (u32)f2bf(v.x) | ((u32)f2bf(v.y) << 16);
  u32 p1 = (u32)f2bf(v.z) | ((u32)f2bf(v.w) << 16);
  uint2 r; r.x = p0; r.y = p1;
  *(uint2*)(out + i) = r;
}

// ------------- tiled transpose + cast: in f32 [R][C] -> out bf16 [C][R] --------
// Write phase packs 4 rows per thread into one uint2 (8B) store.
__global__ void transpose_cast(const float* __restrict__ in, u16* __restrict__ out,
                               int R, int C) {
  __shared__ float tile[32][33];
  const int tx = threadIdx.x & 31, ty = threadIdx.x >> 5;   // 32 x 8 read map
  const int c0 = blockIdx.x * 32, r0 = blockIdx.y * 32;
#pragma unroll
  for (int i = 0; i < 32; i += 8)
    tile[ty + i][tx] = in[(size_t)(r0 + ty + i) * C + c0 + tx];
  __syncthreads();
  // write map: 32 cols x 8 row-groups (4 rows each) -> one uint2 per thread
  const int cl = threadIdx.x >> 3, rg = threadIdx.x & 7;
  const int rb = rg * 4;
  uint2 rr;
  rr.x = pack2bf(tile[rb + 0][cl], tile[rb + 1][cl]);
  rr.y = pack2bf(tile[rb + 2][cl], tile[rb + 3][cl]);
  *(uint2*)(out + (size_t)(c0 + cl) * R + r0 + rb) = rr;
}

// ------- rope cos/sin table: [NTOK][64] each; also zeroes the attn job ctr -----
__global__ void rope_table(const int* __restrict__ positions,
                           float* __restrict__ cs, float* __restrict__ sn,
                           int* __restrict__ ctr) {
  if (blockIdx.x == 0 && threadIdx.x == 0) *ctr = 0;
  int idx = blockIdx.x * 256 + threadIdx.x;   // NTOK*64
  int t = idx >> 6, i = idx & 63;
  float p = (float)positions[t];
  float inv = expf(-(float)i * (13.815510557964274f / 64.f));
  float a = p * inv;
  cs[idx] = cosf(a);
  sn[idx] = sinf(a);
}

// --------- in-place RoPE on qkv (q scaled by D^-0.5 * log2e for exp2-softmax) --
// Vectorized: 16 threads per head-row; uint2 loads/stores + float4 cos/sin.
__global__ void rope_kernel(u16* __restrict__ qkv, const float* __restrict__ cs,
                            const float* __restrict__ sn) {
  const int gtid = blockIdx.x * 256 + threadIdx.x;
  const int hr = gtid >> 4;              // head-row id: NTOK*32
  const int sub = gtid & 15;
  const int t = hr >> 5, hh = hr & 31;
  const size_t base = (size_t)t * QKVW +
                      (hh < NHEAD ? hh * HD : KOFF + (hh - NHEAD) * HD);
  const int d0 = sub * 4;
  uint2 xa = *(const uint2*)(qkv + base + d0);        // x1[d0..d0+3]
  uint2 xb = *(const uint2*)(qkv + base + 64 + d0);   // x2[d0..d0+3]
  float4 c = *(const float4*)(cs + t * 64 + d0);
  float4 s = *(const float4*)(sn + t * 64 + d0);
  float x1[4], x2[4];
  x1[0] = bf2f((u16)xa.x); x1[1] = bf2f((u16)(xa.x >> 16));
  x1[2] = bf2f((u16)xa.y); x1[3] = bf2f((u16)(xa.y >> 16));
  x2[0] = bf2f((u16)xb.x); x2[1] = bf2f((u16)(xb.x >> 16));
  x2[2] = bf2f((u16)xb.y); x2[3] = bf2f((u16)(xb.y >> 16));
  const float cc[4] = {c.x, c.y, c.z, c.w};
  const float ss[4] = {s.x, s.y, s.z, s.w};
  const float sc = (hh < NHEAD) ? QSCALE_L2E : 1.0f;
  float y1[4], y2[4];
#pragma unroll
  for (int i = 0; i < 4; ++i) {
    y1[i] = (x1[i] * cc[i] - x2[i] * ss[i]) * sc;
    y2[i] = (x2[i] * cc[i] + x1[i] * ss[i]) * sc;
  }
  uint2 ra, rb;
  ra.x = pack2bf(y1[0], y1[1]); ra.y = pack2bf(y1[2], y1[3]);
  rb.x = pack2bf(y2[0], y2[1]); rb.y = pack2bf(y2[2], y2[3]);
  *(uint2*)(qkv + base + d0) = ra;
  *(uint2*)(qkv + base + 64 + d0) = rb;
}

// ---------------- 256x256 8-phase MFMA GEMM (m201-class template) --------------
// A [M][Kst] bf16, Bt [Next-rows][Kst] bf16. BK=64, 8 waves (2M x 4N).
// LDS: 2 slots x (A 256x64 + B 256x64) = 128 KiB. Per K-tile: 4 quadrant phases
// of 16 MFMA; one 16KB half staged per phase; counted vmcnt(4) once per tile.
// T2 swizzle slot^=row&7 (pre-swizzled source + XOR read). XCD block swizzle.
// MODE 0: bf16 + bias out (stride ldc).  MODE 1: f32 out (stride ldc).
// MODE 2: split-K f32 partial — grid = tiles x slices; slice ks covers
//         k in [ks*NT*64, (ks+1)*NT*64), output slab at outf + ks*M*Next.
template <int MODE>
__global__ __launch_bounds__(512, 2) void gemm256(
    const u16* __restrict__ A, const u16* __restrict__ Bt,
    const float* __restrict__ bias, u16* __restrict__ outb,
    float* __restrict__ outf, int M, int Next, int Kst, int ldc, int NT) {
  __shared__ __align__(16) u16 Al[2][256 * 64];   // 64 KiB
  __shared__ __align__(16) u16 Bl[2][256 * 64];   // 64 KiB
  const int tid = threadIdx.x;
  const int l = tid & 63, w = tid >> 6;
  const int g = l >> 4, r = l & 15;
  const int wm = w >> 2, wn = w & 3;
  const int nbx = Next >> 8;
  const int cpx = (int)gridDim.x >> 3;            // grid % 8 == 0
  const int bid = ((int)blockIdx.x & 7) * cpx + ((int)blockIdx.x >> 3);
  int bx, by, kbase;
  float* outp = outf;
  if (MODE == 2) {
    const int tps = nbx * (M >> 8);               // tiles per K-slice
    const int ks = bid / tps, rem = bid % tps;
    by = rem / nbx; bx = rem % nbx;
    kbase = ks * (NT << 6);
    outp = outf + (size_t)ks * M * Next;
  } else {
    bx = bid % nbx; by = bid / nbx; kbase = 0;
  }
  const int row0 = by * 256, col0 = bx * 256;

  f32x4 acc[8][4] = {};
  bf16x8 af[4][2];        // A-frags: 4 row-frags x 2 k-halves (one rh quadrant)
  bf16x8 bfr[2][2][2];    // B-frags: [ch][fc][kk] — both col-quadrants held

  // stage one 16KB half (128 rows x 64 k) of A or B for k-tile t
  auto stageU = [&](const u16* mb, int base0, char* ldsMat, int h, int t) {
#pragma unroll
    for (int q = 0; q < 2; ++q) {
      const int idx = q * 512 + tid;              // 0..1023 16B-chunks
      const int rho = h * 128 + (idx >> 3);       // row within 256-row tile
      const int sl = (idx & 7) ^ (rho & 7);       // pre-swizzled source slot
      async16(mb + (size_t)(base0 + rho) * Kst + kbase + t * 64 + sl * 8,
              ldsMat + (size_t)(t & 1) * 32768 + h * 16384 + idx * 16);
    }
  };

#define READ_A(s, rh)                                                           \
  _Pragma("unroll") for (int fr = 0; fr < 4; ++fr) {                            \
    const int row_ = (rh) * 128 + wm * 64 + fr * 16 + r;                        \
    _Pragma("unroll") for (int kk = 0; kk < 2; ++kk) {                          \
      const int sl_ = (kk * 4 + g) ^ (row_ & 7);                                \
      af[fr][kk] = *(const bf16x8*)((const char*)Al + (s) * 32768 +             \
                                    row_ * 128 + sl_ * 16);                     \
    }                                                                           \
  }
#define READ_B(s, ch)                                                           \
  _Pragma("unroll") for (int fc = 0; fc < 2; ++fc) {                            \
    const int col_ = (ch) * 128 + wn * 32 + fc * 16 + r;                        \
    _Pragma("unroll") for (int kk = 0; kk < 2; ++kk) {                          \
      const int sl_ = (kk * 4 + g) ^ (col_ & 7);                                \
      bfr[ch][fc][kk] = *(const bf16x8*)((const char*)Bl + (s) * 32768 +        \
                                         col_ * 128 + sl_ * 16);                \
    }                                                                           \
  }
#define MFMA_Q(rh, ch)                                                          \
  __builtin_amdgcn_s_setprio(1);                                                \
  _Pragma("unroll") for (int fr = 0; fr < 4; ++fr)                              \
  _Pragma("unroll") for (int fc = 0; fc < 2; ++fc)                              \
  _Pragma("unroll") for (int kk = 0; kk < 2; ++kk)                              \
    acc[(rh) * 4 + fr][(ch) * 2 + fc] = __builtin_amdgcn_mfma_f32_16x16x32_bf16( \
        af[fr][kk], bfr[ch][fc][kk], acc[(rh) * 4 + fr][(ch) * 2 + fc], 0, 0, 0);\
  __builtin_amdgcn_s_setprio(0);

  // ---- prologue: tile0 full + tile1 A0,B0; counted drain leaves 4 in flight ---
  stageU(A, row0, (char*)Al, 0, 0); stageU(A, row0, (char*)Al, 1, 0);
  stageU(Bt, col0, (char*)Bl, 0, 0); stageU(Bt, col0, (char*)Bl, 1, 0);
  stageU(A, row0, (char*)Al, 0, 1); stageU(Bt, col0, (char*)Bl, 0, 1);
  SB; asm volatile("s_waitcnt vmcnt(4)" ::: "memory");
  BAR;

  for (int t = 0; t < NT; ++t) {
    const int s = t & 1;
    // phase 1: quad(rh0,ch0); stage A-h1(t+1)
    READ_A(s, 0); READ_B(s, 0);
    if (t + 1 < NT) stageU(A, row0, (char*)Al, 1, t + 1);
    BAR; MFMA_Q(0, 0); BAR;
    // phase 2: quad(rh0,ch1); stage B-h1(t+1)
    READ_B(s, 1);
    if (t + 1 < NT) stageU(Bt, col0, (char*)Bl, 1, t + 1);
    BAR; MFMA_Q(0, 1); BAR;
    // phase 3: quad(rh1,ch0); stage A-h0(t+2)
    READ_A(s, 1);
    if (t + 2 < NT) stageU(A, row0, (char*)Al, 0, t + 2);
    BAR; MFMA_Q(1, 0); BAR;
    // phase 4: quad(rh1,ch1); stage B-h0(t+2)
    if (t + 2 < NT) stageU(Bt, col0, (char*)Bl, 0, t + 2);
    BAR; MFMA_Q(1, 1);
    if (t < NT - 2)        { SB; asm volatile("s_waitcnt vmcnt(4)" ::: "memory"); }
    else if (t == NT - 2)  { SB; asm volatile("s_waitcnt vmcnt(0)" ::: "memory"); }
    BAR;
  }
  SB; asm volatile("s_waitcnt vmcnt(0)" ::: "memory");

  // ---- epilogue ----
#pragma unroll
  for (int m = 0; m < 8; ++m) {
    const int row = row0 + (m >> 2) * 128 + wm * 64 + (m & 3) * 16 + g * 4;
#pragma unroll
    for (int n = 0; n < 4; ++n) {
      const int col = col0 + (n >> 1) * 128 + wn * 32 + (n & 1) * 16 + r;
      const float bb = (MODE == 0) ? bias[col] : 0.f;
#pragma unroll
      for (int j = 0; j < 4; ++j) {
        float v = acc[m][n][j] + bb;
        if (MODE == 0) outb[(size_t)(row + j) * ldc + col] = f2bf(v);
        else           outp[(size_t)(row + j) * ldc + col] = v;
      }
    }
  }
}

// ------- V reduce: sum 4 split-K slabs [NTOK][512] f32 + bias -> vtg bf16 ------
// vtg layout [(b*NKVH+kvh)*HD + d][NS]  (transposed via LDS tile)
__global__ void v_reduce(const float* __restrict__ slabs, const float* __restrict__ bias,
                         u16* __restrict__ vtg) {
  __shared__ float tile[32][33];
  const int tx = threadIdx.x & 31, ty = threadIdx.x >> 5;  // 32 x 8
  const int c0 = blockIdx.x * 32;      // col within 512 (kvh*HD+d)
  const int r0 = blockIdx.y * 32;      // token row within NTOK
#pragma unroll
  for (int i = 0; i < 32; i += 8) {
    const size_t idx = (size_t)(r0 + ty + i) * 512 + c0 + tx;
    float s = slabs[idx] + slabs[idx + VSLAB] + slabs[idx + 2 * VSLAB] +
              slabs[idx + 3 * VSLAB];
    tile[ty + i][tx] = s + bias[VOFF + c0 + tx];
  }
  __syncthreads();
#pragma unroll
  for (int i = 0; i < 32; i += 8) {
    const int col = c0 + ty + i;               // kvh = col>>7, d = col&127
    const int row = r0 + tx;                   // b = row>>11, s = row&2047
    vtg[((size_t)((((row >> 11) * NKVH) + (col >> 7)) * HD + (col & 127))) * NS +
        (row & 2047)] = f2bf(tile[tx][ty + i]);
  }
}

// ---------------- causal GQA flash attention (swapped-operand form) ------------
// ROUND-16 PROVEN CONFIG (140us, session best; reproduced rounds 16 & 19):
// persistent blocks + dynamic heavy-first queue; 8 waves, QBLK=128, KVBLK=64;
// K AND V double-buffered one tile ahead -> SINGLE wait+barrier per tile
// (vmcnt(0)+barrier at loop-top certifies K[cur],V[cur] landed AND buffer
// cur^1 fully read). 64KB LDS -> 2 blocks/CU. Deferred softmax. 76 VGPR.
// Measured-blocked escape routes (do not retry):
//  - rounds 14/17: fewer-waves/more-rows variants (2-frag 16x16, 32x32) hit
//    the VGPR wall (152-156 -> half occupancy, neutral/negative);
//  - round 13: V-dbuf with two barriers/tile = neutral (pipe-bound, not lat);
//  - round 20: V gathered from global = 2.3x regression (latency serialized
//    into PV MFMAs, MfmaUtil 7.9%);
//  - round 18: merging V-GEMM into QK dispatch broke L2 locality (FETCH +70MB).
__global__ __launch_bounds__(512) void attn_kernel(const u16* __restrict__ qkv,
                                                   const u16* __restrict__ vtg,
                                                   u16* __restrict__ Oh,
                                                   int* __restrict__ ctr) {
  __shared__ __align__(16) u16 Ks[2][64 * 128];   // [key][d] swizzled, 16KB each
  __shared__ __align__(16) u16 Vt[2][128 * 64];   // [d][key] swizzled, 16KB each
  __shared__ int s_job;
  const int tid = threadIdx.x, l = tid & 63, w = tid >> 6;   // w 0..7
  const int g = l >> 4, r = l & 15;
  // shuffle sources for the P exchange (same r, groups 2(g&1) and 2(g&1)+1)
  const int srcA = r + ((l & 16) << 1);
  const int srcB = srcA + 16;
  const bool hi = (l & 32) != 0;                 // g>>1

  for (;;) {
    if (tid == 0) s_job = atomicAdd(ctr, 1);
    __syncthreads();                             // also guards LDS reuse across jobs
    const int jid = s_job;
    if (jid >= NJOBS) return;
    const int qtr = jid / 56;
    const int qt = 15 - qtr;                     // heavy jobs grabbed first
    const int bh = jid - qtr * 56;
    const int h = bh % NHEAD, b = bh / NHEAD;
    const int kvh = h / 7;
    const int q0 = qt * 128;

    // Q fragment (B-frag role: col = r = q-row, k = ks*32 + g*8 + i)
    const int qrow = q0 + w * 16 + r;
    const size_t qbase = (size_t)(b * NS + qrow) * QKVW + h * HD;
    bf16x8 qf[4];
#pragma unroll
    for (int ks = 0; ks < 4; ++ks)
      qf[ks] = *(const bf16x8*)(qkv + qbase + ks * 32 + g * 8);

    const u16* kb0 = qkv + (size_t)(b * NS) * QKVW + KOFF + kvh * HD;
    const u16* vb0 = vtg + (size_t)((b * NKVH + kvh) * HD) * NS;

    // per-thread staging pointers (advance by constant stride per tile)
    const u16* kap[2];
    const u16* vap[2];
#pragma unroll
    for (int i = 0; i < 2; ++i) {
      const int li = (w * 2 + i) * 64 + l;       // 0..1023 chunk id
      const int rr = li >> 4, c = li & 15;
      kap[i] = kb0 + (size_t)rr * QKVW + ((c ^ (rr & 7)) << 3);
      const int d = li >> 3, c2 = li & 7;
      vap[i] = vb0 + (size_t)d * NS + ((c2 ^ (d & 7)) << 3);
    }

    f32x4 oacc[8] = {};         // O^T: oacc[dt][j] = O[qrow=r][d=dt*16+4g+j]
    float mrun = -1e30f, lsum = 0.f;

    const int nkv = 2 * qt + 2;

    auto stageK = [&](u16* kdst) {
#pragma unroll
      for (int i = 0; i < 2; ++i) {
        async16(kap[i], (char*)kdst + (w * 2 + i) * 1024);
        kap[i] += 64 * QKVW;
      }
    };
    auto stageV = [&](u16* vdst) {
#pragma unroll
      for (int i = 0; i < 2; ++i) {
        async16(vap[i], (char*)vdst + (w * 2 + i) * 1024);
        vap[i] += 64;
      }
    };

    // prologue: K(0), V(0)
    stageK(Ks[0]); stageV(Vt[0]);
    int cur = 0;

    for (int kvt = 0; kvt < nkv; ++kvt) {
      const int kv0 = kvt * 64;
      // single per-tile sync: my 4 staged chunks (K[cur],V[cur]) landed;
      // barrier => everyone's landed AND buffer cur^1 fully read last iter.
      asm volatile("s_waitcnt vmcnt(0)" ::: "memory");
      __builtin_amdgcn_s_barrier();
      __builtin_amdgcn_sched_barrier(0);

      const bool haveNext = (kvt + 1 < nkv);
      if (haveNext) { stageK(Ks[cur ^ 1]); stageV(Vt[cur ^ 1]); }

      // wave fully below this KV tile? (rows all masked) -> skip compute
      const bool active = kv0 <= q0 + w * 16 + 15;

      if (active) {
        // ---- QK^T swapped: sacc[n] = S^T[key=n*16+4g+j][qrow=r] ----
        f32x4 sacc[4] = {};
        const char* ksB = (const char*)Ks[cur];
        __builtin_amdgcn_s_setprio(1);
#pragma unroll
        for (int n = 0; n < 4; ++n) {
          const int key = n * 16 + r;
          const int sw = (key & 7) << 4;
#pragma unroll
          for (int ks = 0; ks < 4; ++ks) {
            bf16x8 kf = *(const bf16x8*)(ksB + key * 256 + ((ks * 64 + g * 16) ^ sw));
            sacc[n] = __builtin_amdgcn_mfma_f32_16x16x32_bf16(kf, qf[ks], sacc[n], 0, 0, 0);
          }
        }
        __builtin_amdgcn_s_setprio(0);
        // ---- causal mask (exact per-wave diagonal predicate) ----
        if (kv0 + 63 > q0 + w * 16) {
#pragma unroll
          for (int n = 0; n < 4; ++n) {
            const int key_g = kv0 + n * 16 + g * 4;
#pragma unroll
            for (int j = 0; j < 4; ++j)
              if (key_g + j > qrow) sacc[n][j] = -1e30f;
          }
        }
        // ---- per-lane online softmax (exp2 domain), deferred reductions ----
        float mx = fmaxf(fmaxf(sacc[0][0], sacc[0][1]), fmaxf(sacc[0][2], sacc[0][3]));
#pragma unroll
        for (int n = 1; n < 4; ++n)
          mx = fmaxf(mx, fmaxf(fmaxf(sacc[n][0], sacc[n][1]), fmaxf(sacc[n][2], sacc[n][3])));
        if (!__all(mx <= mrun + 8.0f)) {        // rare: row max grew
          mx = fmaxf(mx, __shfl_xor(mx, 16, 64));
          mx = fmaxf(mx, __shfl_xor(mx, 32, 64));   // row-uniform max
          const float mnew = fmaxf(mrun, mx);
          const float scale = __builtin_amdgcn_exp2f(mrun - mnew);
          mrun = mnew;
          lsum *= scale;
#pragma unroll
          for (int dt = 0; dt < 8; ++dt) oacc[dt] *= scale;
        }
#pragma unroll
        for (int n = 0; n < 4; ++n)
#pragma unroll
          for (int j = 0; j < 4; ++j) {
            float p = __builtin_amdgcn_exp2f(sacc[n][j] - mrun);  // bounded 2^8
            sacc[n][j] = p;
            lsum += p;
          }

        // ---- pack P to bf16 pairs (v_cvt_pk), exchange to PV B-frags in-reg ----
        u32 pk[4][2];
#pragma unroll
        for (int n = 0; n < 4; ++n) {
          pk[n][0] = pack2bf(sacc[n][0], sacc[n][1]);
          pk[n][1] = pack2bf(sacc[n][2], sacc[n][3]);
        }
        union { u32 wrd[4]; bf16x8 v; } pf[2];
#pragma unroll
        for (int ks2 = 0; ks2 < 2; ++ks2) {
          const int n0 = 2 * ks2, n1 = 2 * ks2 + 1;
#pragma unroll
          for (int hh2 = 0; hh2 < 2; ++hh2) {
            u32 a0 = (u32)__shfl((int)pk[n0][hh2], srcA, 64);
            u32 a1 = (u32)__shfl((int)pk[n1][hh2], srcA, 64);
            pf[ks2].wrd[hh2] = hi ? a1 : a0;
            u32 b0 = (u32)__shfl((int)pk[n0][hh2], srcB, 64);
            u32 b1 = (u32)__shfl((int)pk[n1][hh2], srcB, 64);
            pf[ks2].wrd[2 + hh2] = hi ? b1 : b0;
          }
        }

        // ---- PV swapped: no barrier needed — V[cur] certified at loop-top ----
        const char* vtB = (const char*)Vt[cur];
        __builtin_amdgcn_s_setprio(1);
#pragma unroll
        for (int ks2 = 0; ks2 < 2; ++ks2) {
#pragma unroll
          for (int dt = 0; dt < 8; ++dt) {
            const int d = dt * 16 + r;
            bf16x8 vf = *(const bf16x8*)(vtB + d * 128 +
                                         ((ks2 * 64 + g * 16) ^ ((d & 7) << 4)));
            oacc[dt] = __builtin_amdgcn_mfma_f32_16x16x32_bf16(vf, pf[ks2].v, oacc[dt], 0, 0, 0);
          }
        }
        __builtin_amdgcn_s_setprio(0);
      }
      cur ^= 1;
    }

    // ---- epilogue: reduce l across the row's 4 lanes, write O^T -> Oh ----
    float lr = lsum;
    lr += __shfl_xor(lr, 16, 64);
    lr += __shfl_xor(lr, 32, 64);
    const float inv = 1.f / lr;
    const size_t obase = (size_t)(b * NS + qrow) * QSZ + h * HD;
#pragma unroll
    for (int dt = 0; dt < 8; ++dt) {
      uint2 r2;
      r2.x = pack2bf(oacc[dt][0] * inv, oacc[dt][1] * inv);
      r2.y = pack2bf(oacc[dt][2] * inv, oacc[dt][3] * inv);
      *(uint2*)(Oh + obase + dt * 16 + 4 * g) = r2;
    }
  }
}

// -------------------------------------------------------------------------------
extern "C" void kernel_launch(void* const* d_in, const int* in_sizes, int n_in,
                              void* d_out, int out_size, void* d_ws, size_t ws_size,
                              hipStream_t stream) {
  const int* positions = (const int*)d_in[0];
  const float* hidden = (const float*)d_in[1];
  const float* w_qkv = (const float*)d_in[2];
  const float* b_qkv = (const float*)d_in[3];
  const float* w_o = (const float*)d_in[4];
  float* out = (float*)d_out;

  char* ws = (char*)d_ws;
  const size_t XB_OFF = 0;                           // 29,360,128 B (later reused by WoT)
  const size_t WQT_OFF = 29360128;                   // 33,030,144 B (later reused by Oh)
  const size_t QKV_OFF = WQT_OFF + 33030144;         // 37,748,736 B
  const size_t CS_OFF = QKV_OFF + 37748736;          // 1,048,576 B
  const size_t SN_OFF = CS_OFF + 1048576;            // 1,048,576 B
  const size_t CTR_OFF = SN_OFF + 1048576;           // 64 B (attn job counter)
  const size_t WS_NEED = CTR_OFF + 64;               // ~102.2 MB (known-safe)
  if (ws_size < WS_NEED) return;

  u16* Xb = (u16*)(ws + XB_OFF);
  u16* WoT = (u16*)(ws + XB_OFF);    // alias: after GEMMs consumed Xb
  u16* WqT = (u16*)(ws + WQT_OFF);
  u16* Oh = (u16*)(ws + WQT_OFF);    // alias: after GEMMs consumed WqT
  u16* qkvb = (u16*)(ws + QKV_OFF);
  float* cs = (float*)(ws + CS_OFF);
  float* sn = (float*)(ws + SN_OFF);
  int* ctr = (int*)(ws + CTR_OFF);
  // d_out scratch: vtg (4MB) + 4 split-K V slabs (32MB); GEMM2 overwrites later.
  u16* vtg = (u16*)d_out;
  float* vslabs = (float*)((char*)d_out + 4194304);

  cast_f32_bf16<<<14336, 256, 0, stream>>>(hidden, Xb);
  transpose_cast<<<dim3(QKVW / 32, HIDDEN_DIM / 32), 256, 0, stream>>>(w_qkv, WqT, HIDDEN_DIM, QKVW);
  rope_table<<<(NTOK * 64) / 256, 256, 0, stream>>>(positions, cs, sn, ctr);

  // Q+K projection (+bias): N extent 4096 -> grid 16x16 = 256, zero tail
  gemm256<0><<<256, 512, 0, stream>>>(
      Xb, WqT, b_qkv, qkvb, nullptr, NTOK, 4096, HIDDEN_DIM, QKVW, HIDDEN_DIM / 64);

  // V projection: split-K=4 partials (grid 2x16 tiles x 4 slices = 128 blocks)
  gemm256<2><<<128, 512, 0, stream>>>(
      Xb, WqT + (size_t)VOFF * HIDDEN_DIM, nullptr, nullptr, vslabs,
      NTOK, 512, HIDDEN_DIM, 512, HIDDEN_DIM / 64 / 4);

  // reduce slabs + bias -> vtg (transposed [b,kvh,d][s])
  v_reduce<<<dim3(512 / 32, NTOK / 32), 256, 0, stream>>>(vslabs, b_qkv, vtg);

  // vectorized RoPE on Q,K: 16 threads/head-row, 8192 blocks
  rope_kernel<<<(NTOK * 32 * 16) / 256, 256, 0, stream>>>(qkvb, cs, sn);

  transpose_cast<<<dim3(HIDDEN_DIM / 32, QSZ / 32), 256, 0, stream>>>(w_o, WoT, QSZ, HIDDEN_DIM);

  // persistent attn: 512 blocks (2/CU at 64KB LDS), single-barrier-per-tile
  attn_kernel<<<ATTN_BLOCKS, 512, 0, stream>>>(qkvb, vtg, Oh, ctr);

  gemm256<1><<<(HIDDEN_DIM / 256) * (NTOK / 256), 512, 0, stream>>>(
      Oh, WoT, nullptr, nullptr, out, NTOK, HIDDEN_DIM, QSZ, HIDDEN_DIM, QSZ / 64);
}